// Round 4
// baseline (241.875 us; speedup 1.0000x reference)
//
#include <hip/hip_runtime.h>
#include <hip/hip_bf16.h>
#include <stdint.h>

typedef __bf16 bf16;
typedef bf16 bf16x8 __attribute__((ext_vector_type(8)));
typedef float f32x4 __attribute__((ext_vector_type(4)));

#define LOGSQRT2PI 0.9189385332046727f

__device__ __forceinline__ void gload_lds16(const void* g, void* l) {
    __builtin_amdgcn_global_load_lds((__attribute__((address_space(1))) void*)g,
                                     (__attribute__((address_space(3))) void*)l,
                                     16, 0, 0);
}

// ---- zero d_out (y region + the two scalar accumulators) ----
__global__ void k_zero(float* p, int n) {
    int stride = gridDim.x * blockDim.x;
    for (int i = blockIdx.x * blockDim.x + threadIdx.x; i < n; i += stride) p[i] = 0.f;
}

// ---- weight prep: W = mu + (1e-6+softplus(p))*eps ; write Wt[n][k] bf16 ;
// ---- accumulate lqw/lpw into osc[0]/osc[1] ----
__global__ void k_prep(const float* __restrict__ mu, const float* __restrict__ p,
                       const float* __restrict__ eps, bf16* __restrict__ Wt,
                       int K, int N, int Npad, float* __restrict__ osc) {
    int total = K * Npad;
    float lqw = 0.0f, lpw = 0.0f;
    for (int idx = blockIdx.x * blockDim.x + threadIdx.x; idx < total;
         idx += gridDim.x * blockDim.x) {
        int k = idx / Npad;
        int n = idx - k * Npad;
        float w = 0.0f;
        if (n < N) {
            int src = k * N + n;
            float m = mu[src];
            float e = eps[src];
            float sd = 1e-6f + log1pf(expf(p[src]));
            w = m + sd * e;
            float z = (w - m) / sd;
            lqw += -LOGSQRT2PI - logf(sd) - 0.5f * z * z;
            lpw += -LOGSQRT2PI - 0.5f * w * w;
        }
        Wt[n * K + k] = (bf16)w;
    }
    #pragma unroll
    for (int off = 32; off; off >>= 1) {
        lqw += __shfl_down(lqw, off);
        lpw += __shfl_down(lpw, off);
    }
    if ((threadIdx.x & 63) == 0) {
        atomicAdd(&osc[0], lqw);
        atomicAdd(&osc[1], lpw);
    }
}

// ---- x fp32 -> bf16 ----
typedef bf16 bf16x4 __attribute__((ext_vector_type(4)));
__global__ void k_cvt(const float4* __restrict__ in, bf16x4* __restrict__ out, int n4) {
    int stride = gridDim.x * blockDim.x;
    for (int i = blockIdx.x * blockDim.x + threadIdx.x; i < n4; i += stride) {
        float4 v = in[i];
        bf16x4 o;
        o[0] = (bf16)v.x; o[1] = (bf16)v.y; o[2] = (bf16)v.z; o[3] = (bf16)v.w;
        out[i] = o;
    }
}

// ============================================================================
// 128x128-tile GEMM, 4 waves (2Mx2N), BK=64 (2 ks-halves of 32), double-buffered
// 64 KB LDS -> 2 blocks/CU (independent barrier domains hide each other's stalls).
//
// LDS: chunk = 1024B = one wave ds_read_b128 region (conflict-free), fragment
// ordered: A chunk(rg,ks) at elems (rg*2+ks)*512, rg=row/16 (0..7); lane l holds
// A[rg*16+(l&15)][kt*64+ks*32+(l>>4)*8 ..+8] at chunk+l*8.  B identical (rows=cols).
// A: [buf*8192 + chunk*512], B: [16384 + buf*8192 + chunk*512].
//
// Staging unit STG(T,ks,buf) = 4 gloads/thread (A-half 2 + B-half 2, wave w
// covers rg=w*2+s).  Pipeline (prologue stages T0.ks0,T0.ks1,T1.ks0):
//   T.ph0: read ks0 frags; STG(T+1, ks1 -> nb);   [nb's old data fully read]
//   T.ph1: read ks1 frags; STG(T+2, ks0 -> buf);  [buf.ks0 read in ph0 - disjoint]
// Gate derivation (4 gloads/batch): phase-end gate protects the NEXT phase's
// reads; the needed batch always has exactly 2 newer batches => vmcnt(8)
// uniformly; tail clamps 8->4->0.
// ============================================================================
template<bool RELU, bool FUSE3>
__global__ __launch_bounds__(256, 2)
void k_g128(const bf16* __restrict__ A, const bf16* __restrict__ Bt,
            bf16* __restrict__ C, const bf16* __restrict__ W3t,
            float* __restrict__ Y) {
    __shared__ __align__(16) bf16 LDSe[32768];   // 64 KB
    const int tid = threadIdx.x;
    const int l = tid & 63, w = tid >> 6;
    const int wm = w >> 1, wn = w & 1;
    const int l8 = l * 8;

    // bijective XCD swizzle (2048 % 8 == 0); consecutive logical on one XCD
    // share the same A-panel across the 4 bn tiles -> L2 reuse.
    const int bid = blockIdx.x;
    const int logical = (bid & 7) * 256 + (bid >> 3);
    const long bm = (long)(logical >> 2) * 128;
    const int  bn = (logical & 3) * 128;

    const bf16* Asrc = A  + (bm + (l & 15)) * 512 + ((l >> 4) * 8);
    const bf16* Bsrc = Bt + ((long)bn + (l & 15)) * 512 + ((l >> 4) * 8);

    #define STG(T, KS, BUF) do {                                               \
        _Pragma("unroll")                                                      \
        for (int s = 0; s < 2; s++) {                                          \
            int rg = w * 2 + s;                                                \
            gload_lds16(Asrc + rg * (16 * 512) + (T) * 64 + (KS) * 32,         \
                        &LDSe[(BUF) * 8192 + (rg * 2 + (KS)) * 512 + l8]);     \
            gload_lds16(Bsrc + rg * (16 * 512) + (T) * 64 + (KS) * 32,         \
                        &LDSe[16384 + (BUF) * 8192 + (rg * 2 + (KS)) * 512 + l8]); \
        } } while (0)

    #define LOADA(KS) { _Pragma("unroll")                                      \
        for (int i = 0; i < 4; i++)                                            \
            afr[i] = *(const bf16x8*)&LDSe[buf * 8192 +                        \
                     ((wm * 4 + i) * 2 + (KS)) * 512 + l8]; }
    #define LOADB(KS) { _Pragma("unroll")                                      \
        for (int j = 0; j < 4; j++)                                            \
            bfr[j] = *(const bf16x8*)&LDSe[16384 + buf * 8192 +                \
                     ((wn * 4 + j) * 2 + (KS)) * 512 + l8]; }
    #define MFMA16 { _Pragma("unroll")                                         \
        for (int i = 0; i < 4; i++)                                            \
            _Pragma("unroll")                                                  \
            for (int j = 0; j < 4; j++)                                        \
                acc[i][j] = __builtin_amdgcn_mfma_f32_16x16x32_bf16(           \
                    afr[i], bfr[j], acc[i][j], 0, 0, 0); }

    f32x4 acc[4][4];
    #pragma unroll
    for (int i = 0; i < 4; i++)
        #pragma unroll
        for (int j = 0; j < 4; j++) acc[i][j] = (f32x4){0.f, 0.f, 0.f, 0.f};
    bf16x8 afr[4], bfr[4];

    // prologue
    STG(0, 0, 0); STG(0, 1, 0); STG(1, 0, 1);
    asm volatile("s_waitcnt vmcnt(8)" ::: "memory");   // T0.ks0 landed
    __builtin_amdgcn_s_barrier();

    for (int T = 0; T < 8; ++T) {
        const int buf = T & 1, nb = buf ^ 1;
        // ph0: ks0
        LOADA(0); LOADB(0);
        if (T < 7) STG(T + 1, 1, nb);
        __builtin_amdgcn_s_barrier();
        __builtin_amdgcn_s_setprio(1); MFMA16; __builtin_amdgcn_s_setprio(0);
        if (T < 7) { asm volatile("s_waitcnt vmcnt(8)" ::: "memory"); }
        else       { asm volatile("s_waitcnt vmcnt(0)" ::: "memory"); }
        __builtin_amdgcn_s_barrier();
        // ph1: ks1
        LOADA(1); LOADB(1);
        if (T < 6) STG(T + 2, 0, buf);
        __builtin_amdgcn_s_barrier();
        __builtin_amdgcn_s_setprio(1); MFMA16; __builtin_amdgcn_s_setprio(0);
        if (T < 6)       { asm volatile("s_waitcnt vmcnt(8)" ::: "memory"); }
        else if (T == 6) { asm volatile("s_waitcnt vmcnt(4)" ::: "memory"); }
        __builtin_amdgcn_s_barrier();
    }

    // ---- epilogue: acc -> LDS bf16 tile [128][128] (ReLU, 16B-chunk swizzle
    // phys_chunk = cc ^ (row&7); measured conflict-free round 3) ----
    #pragma unroll
    for (int i = 0; i < 4; i++)
        #pragma unroll
        for (int j = 0; j < 4; j++)
            #pragma unroll
            for (int q = 0; q < 4; q++) {
                int row = wm * 64 + i * 16 + (l >> 4) * 4 + q;
                int col = wn * 64 + j * 16 + (l & 15);
                float v = acc[i][j][q];
                if (RELU) v = fmaxf(v, 0.f);
                LDSe[row * 128 + ((col >> 3) ^ (row & 7)) * 8 + (col & 7)] = (bf16)v;
            }
    __syncthreads();

    if (!FUSE3) {
        // coalesced dwordx4 stores: 16 rows per iter (16 lanes x 16B per row-seg)
        #pragma unroll
        for (int it = 0; it < 8; it++) {
            int row = it * 16 + (tid >> 4);
            int cc = tid & 15;
            bf16x8 v = *(const bf16x8*)&LDSe[row * 128 + ((cc ^ (row & 7)) * 8)];
            *(bf16x8*)(C + (bm + row) * 512 + bn + cc * 8) = v;
        }
    } else {
        // layer-3 partial: y[rows][0..9] += h2[rows][bn..bn+127] @ W3t[.][bn..]
        bf16x8 b3[4];
        #pragma unroll
        for (int ks = 0; ks < 4; ks++)
            b3[ks] = *(const bf16x8*)(W3t + (l & 15) * 512 + bn + ks * 32 + (l >> 4) * 8);
        f32x4 yacc[2];
        yacc[0] = (f32x4){0.f, 0.f, 0.f, 0.f};
        yacc[1] = (f32x4){0.f, 0.f, 0.f, 0.f};
        #pragma unroll
        for (int fr = 0; fr < 2; fr++)
            #pragma unroll
            for (int ks = 0; ks < 4; ks++) {
                int row = w * 32 + fr * 16 + (l & 15);
                int cc = ks * 4 + (l >> 4);
                bf16x8 a3 = *(const bf16x8*)&LDSe[row * 128 + ((cc ^ (row & 7)) * 8)];
                yacc[fr] = __builtin_amdgcn_mfma_f32_16x16x32_bf16(a3, b3[ks], yacc[fr], 0, 0, 0);
            }
        if ((l & 15) < 10) {
            #pragma unroll
            for (int fr = 0; fr < 2; fr++)
                #pragma unroll
                for (int q = 0; q < 4; q++) {
                    long row = bm + w * 32 + fr * 16 + (l >> 4) * 4 + q;
                    atomicAdd(Y + row * 10 + (l & 15), yacc[fr][q]);
                }
        }
    }
    #undef STG
    #undef LOADA
    #undef LOADB
    #undef MFMA16
}

extern "C" void kernel_launch(void* const* d_in, const int* in_sizes, int n_in,
                              void* d_out, int out_size, void* d_ws, size_t ws_size,
                              hipStream_t stream) {
    const float* x   = (const float*)d_in[0];
    const float* mu1 = (const float*)d_in[1];
    const float* p1  = (const float*)d_in[2];
    const float* e1  = (const float*)d_in[3];
    const float* mu2 = (const float*)d_in[4];
    const float* p2  = (const float*)d_in[5];
    const float* e2  = (const float*)d_in[6];
    const float* mu3 = (const float*)d_in[7];
    const float* p3  = (const float*)d_in[8];
    const float* e3  = (const float*)d_in[9];
    float* out = (float*)d_out;

    const int B = 65536, D = 512, DO = 10, DOP = 16;

    char* ws = (char*)d_ws;
    bf16* Wt1 = (bf16*)(ws);
    bf16* Wt2 = (bf16*)(ws + 524288);
    bf16* Wt3 = (bf16*)(ws + 1048576);
    bf16* xb  = (bf16*)(ws + 1114112);
    bf16* h1  = (bf16*)(ws + 1114112 + 67108864);

    float* osc = out + (long)B * DO;

    hipLaunchKernelGGL(k_zero, dim3(512), dim3(256), 0, stream, out, out_size);
    hipLaunchKernelGGL(k_prep, dim3(256), dim3(256), 0, stream, mu1, p1, e1, Wt1, D, D,  D,   osc);
    hipLaunchKernelGGL(k_prep, dim3(256), dim3(256), 0, stream, mu2, p2, e2, Wt2, D, D,  D,   osc);
    hipLaunchKernelGGL(k_prep, dim3(16),  dim3(256), 0, stream, mu3, p3, e3, Wt3, D, DO, DOP, osc);
    hipLaunchKernelGGL(k_cvt, dim3(2048), dim3(256), 0, stream,
                       (const float4*)x, (bf16x4*)xb, B * D / 4);
    hipLaunchKernelGGL((k_g128<true, false>), dim3(2048), dim3(256), 0, stream,
                       xb, Wt1, h1, (const bf16*)nullptr, (float*)nullptr);
    hipLaunchKernelGGL((k_g128<true, true>), dim3(2048), dim3(256), 0, stream,
                       h1, Wt2, (bf16*)nullptr, Wt3, out);
}